// Round 2
// baseline (636.484 us; speedup 1.0000x reference)
//
#include <hip/hip_runtime.h>
#include <hip/hip_bf16.h>
#include <math.h>

// ---------------------------------------------------------------------------
// GCN forward on MI355X (fp32 end-to-end; no fp32 MFMA on CDNA4).
// Pipeline:
//   deg -> scan -> CSR fill (by dst, self-loops included)
//   h = x @ W_enc + b_enc                      [k_gemm<64>, X+W in LDS]
//   2x: hw = (bnrelu?(h) @ Wc[l]) * dinv[row]  [k_gemm<128>, BN of prev layer
//                                               fused into X staging]
//       h = gather-sum(hw[col]) * dinv + bc    [k_agg, BN stats fused]
//       bnfinal -> scale/shift
//   pool (BN+ReLU fused) -> MLP head -> sigmoid
// ---------------------------------------------------------------------------

__global__ __launch_bounds__(256) void k_init(int* __restrict__ deg,
                                              float* __restrict__ pooled,
                                              float* __restrict__ bnstat,
                                              int N) {
  int i = blockIdx.x * 256 + threadIdx.x;
  if (i < N) deg[i] = 1;           // self-loop
  if (i < 64 * 128) pooled[i] = 0.f;
  if (i < 512) bnstat[i] = 0.f;    // sum/sumsq for both layers
}

__global__ __launch_bounds__(256) void k_deg(const int* __restrict__ ei, int E,
                                             int* __restrict__ deg) {
  int i = blockIdx.x * 256 + threadIdx.x;
  if (i < E) atomicAdd(&deg[ei[E + i]], 1);   // dst row
}

// ---- 3-kernel exclusive scan over deg[N] -> rowptr ----
__global__ __launch_bounds__(256) void k_scan_a(const int* __restrict__ deg, int N,
                                                int* __restrict__ rowptr,
                                                int* __restrict__ blksum) {
  __shared__ int s[256];
  int t = threadIdx.x;
  int i = blockIdx.x * 256 + t;
  int v = (i < N) ? deg[i] : 0;
  s[t] = v;
  __syncthreads();
  for (int off = 1; off < 256; off <<= 1) {
    int x = (t >= off) ? s[t - off] : 0;
    __syncthreads();
    s[t] += x;
    __syncthreads();
  }
  if (i < N) rowptr[i] = s[t] - v;            // exclusive (partial)
  if (t == 255) blksum[blockIdx.x] = s[255];
}

__global__ __launch_bounds__(256) void k_scan_b(int* __restrict__ blksum, int nb) {
  __shared__ int s[256];
  int t = threadIdx.x;
  int v = (t < nb) ? blksum[t] : 0;
  s[t] = v;
  __syncthreads();
  for (int off = 1; off < 256; off <<= 1) {
    int x = (t >= off) ? s[t - off] : 0;
    __syncthreads();
    s[t] += x;
    __syncthreads();
  }
  if (t < nb) blksum[t] = s[t] - v;           // exclusive
}

__global__ __launch_bounds__(256) void k_scan_c(const int* __restrict__ deg, int N,
                                                int total,
                                                const int* __restrict__ blksum,
                                                int* __restrict__ rowptr,
                                                int* __restrict__ cursor,
                                                float* __restrict__ dinv) {
  int i = blockIdx.x * 256 + threadIdx.x;
  if (i < N) {
    int rp = rowptr[i] + blksum[blockIdx.x];
    rowptr[i] = rp;
    cursor[i] = rp;
    dinv[i] = rsqrtf((float)deg[i]);
  } else if (i == N) {
    rowptr[N] = total;
  }
}

__global__ __launch_bounds__(256) void k_fill(const int* __restrict__ ei, int E, int N,
                                              int* __restrict__ cursor,
                                              int* __restrict__ colx) {
  int i = blockIdx.x * 256 + threadIdx.x;
  if (i < E) {
    int s = ei[i];
    int d = ei[E + i];
    int pos = atomicAdd(&cursor[d], 1);
    colx[pos] = s;
  } else if (i < E + N) {
    int j = i - E;
    int pos = atomicAdd(&cursor[j], 1);
    colx[pos] = j;                           // self-loop entry
  }
}

// ---- GEMM: Y[N][128] = f(X)[N][K] @ W[K][128] (+bias) (*scale[row]) ----
// f = BN(scale/shift)+ReLU applied during X staging when scsh != nullptr.
// block=256 (4 waves), 32 rows/block. W and X tile both in LDS.
// Inner loop per 4 k's: 8x ds_read_b128 (X, wave-uniform broadcast) +
// 4x ds_read_b64 (W) + 64 FMA -> compute-bound.
template <int K>
__global__ __launch_bounds__(256) void k_gemm(const float* __restrict__ X,
                                              const float* __restrict__ W,
                                              const float* __restrict__ bias,
                                              const float* __restrict__ scale,
                                              const float* __restrict__ scsh,
                                              float* __restrict__ Y, int N) {
  __shared__ float Wl[K * 128];
  __shared__ float Xl[32 * K];
  const int K4 = K / 4;

  for (int i = threadIdx.x; i < K * 32; i += 256)   // K*128/4 float4s
    ((float4*)Wl)[i] = ((const float4*)W)[i];

  int rowBlk = blockIdx.x * 32;
  for (int i = threadIdx.x; i < 32 * K4; i += 256) {
    int r = i / K4, c4 = i - r * K4;
    int row = rowBlk + r;
    if (row >= N) row = N - 1;                      // clamp (writes guarded)
    float4 v = ((const float4*)(X + (size_t)row * K))[c4];
    if (scsh) {                                     // fused BN+ReLU of prev layer
      float4 sc = ((const float4*)scsh)[c4];
      float4 sh = ((const float4*)(scsh + 128))[c4];
      v.x = fmaxf(fmaf(v.x, sc.x, sh.x), 0.f);
      v.y = fmaxf(fmaf(v.y, sc.y, sh.y), 0.f);
      v.z = fmaxf(fmaf(v.z, sc.z, sh.z), 0.f);
      v.w = fmaxf(fmaf(v.w, sc.w, sh.w), 0.f);
    }
    ((float4*)Xl)[i] = v;
  }
  __syncthreads();

  int lane = threadIdx.x & 63;
  int wv = threadIdx.x >> 6;
  int c0 = 2 * lane;
  int lr0 = wv * 8;
  int rowBase = rowBlk + lr0;

  float2 bb = make_float2(0.f, 0.f);
  if (bias) bb = *(const float2*)&bias[c0];

  float a0[8], a1[8];
#pragma unroll
  for (int r = 0; r < 8; r++) { a0[r] = bb.x; a1[r] = bb.y; }

  for (int k = 0; k < K; k += 4) {
    float4 xv[8];
#pragma unroll
    for (int r = 0; r < 8; r++)
      xv[r] = *(const float4*)&Xl[(lr0 + r) * K + k];
    float2 w[4];
#pragma unroll
    for (int j = 0; j < 4; j++)
      w[j] = *(const float2*)&Wl[(k + j) * 128 + c0];
#pragma unroll
    for (int r = 0; r < 8; r++) {
      a0[r] += xv[r].x * w[0].x; a1[r] += xv[r].x * w[0].y;
      a0[r] += xv[r].y * w[1].x; a1[r] += xv[r].y * w[1].y;
      a0[r] += xv[r].z * w[2].x; a1[r] += xv[r].z * w[2].y;
      a0[r] += xv[r].w * w[3].x; a1[r] += xv[r].w * w[3].y;
    }
  }

#pragma unroll
  for (int r = 0; r < 8; r++) {
    int row = rowBase + r;
    if (row < N) {
      float s = scale ? scale[row] : 1.f;
      *(float2*)&Y[(size_t)row * 128 + c0] = make_float2(a0[r] * s, a1[r] * s);
    }
  }
}

// ---- Aggregate + fused BN stats ----
// Y[i] = (sum over CSR row i of HWs[col]) * dinv[i] + bias ; accumulate
// per-channel sum/sumsq of Y into stat[256] (block LDS reduce -> atomics).
__global__ __launch_bounds__(256) void k_agg(const float* __restrict__ HWs,
                                             const int* __restrict__ rowptr,
                                             const int* __restrict__ colx,
                                             const float* __restrict__ dinv,
                                             const float* __restrict__ bias,
                                             float* __restrict__ Y, int N,
                                             float* __restrict__ stat) {
  int lane = threadIdx.x & 63;
  int wv = threadIdx.x >> 6;
  int wid = blockIdx.x * 4 + wv;
  int nw = gridDim.x * 4;
  int c0 = 2 * lane;
  float2 bb = *(const float2*)&bias[c0];

  float s0a = 0.f, s1a = 0.f, q0a = 0.f, q1a = 0.f;
  for (int i = wid; i < N; i += nw) {
    int beg = rowptr[i];
    int end = rowptr[i + 1];
    float s0 = 0.f, s1 = 0.f;
    for (int e = beg; e < end; e++) {
      int s = colx[e];
      float2 v = *(const float2*)&HWs[(size_t)s * 128 + c0];
      s0 += v.x;
      s1 += v.y;
    }
    float di = dinv[i];
    float o0 = fmaf(s0, di, bb.x);
    float o1 = fmaf(s1, di, bb.y);
    *(float2*)&Y[(size_t)i * 128 + c0] = make_float2(o0, o1);
    s0a += o0; s1a += o1;
    q0a += o0 * o0; q1a += o1 * o1;
  }

  __shared__ float red[4][256];   // [wave][ch 0..127 = sum, 128..255 = sumsq]
  red[wv][c0] = s0a;
  red[wv][c0 + 1] = s1a;
  red[wv][128 + c0] = q0a;
  red[wv][128 + c0 + 1] = q1a;
  __syncthreads();
  int t = threadIdx.x;
  float v = red[0][t] + red[1][t] + red[2][t] + red[3][t];
  atomicAdd(&stat[t], v);
}

__global__ __launch_bounds__(128) void k_bnfinal(const float* __restrict__ stat,
                                                 const float* __restrict__ gamma,
                                                 const float* __restrict__ beta,
                                                 float invN,
                                                 float* __restrict__ scsh) {
  int c = threadIdx.x;
  float mu = stat[c] * invN;
  float var = stat[128 + c] * invN - mu * mu;
  float sc = rsqrtf(var + 1e-5f) * gamma[c];
  scsh[c] = sc;
  scsh[128 + c] = beta[c] - mu * sc;
}

// ---- Pool (fused BN+ReLU of last layer) ----
__global__ __launch_bounds__(128) void k_gstart(const int* __restrict__ batch, int N,
                                                int* __restrict__ gstart) {
  int g = threadIdx.x;
  if (g <= 64) {
    int lo = 0, hi = N;
    while (lo < hi) {
      int mid = (lo + hi) >> 1;
      if (batch[mid] < g) lo = mid + 1;
      else hi = mid;
    }
    gstart[g] = lo;   // lower_bound; gstart[64] == N
  }
}

__global__ __launch_bounds__(128) void k_pool(const float* __restrict__ H,
                                              const float* __restrict__ scsh,
                                              const int* __restrict__ gstart,
                                              float* __restrict__ pooled) {
  int g = blockIdx.x >> 3;
  int part = blockIdx.x & 7;
  int c = threadIdx.x;
  float sc = scsh[c], sh = scsh[128 + c];
  int beg = gstart[g], end = gstart[g + 1];
  int len = end - beg;
  int pbeg = beg + (len * part) / 8;
  int pend = beg + (len * (part + 1)) / 8;
  float s = 0.f;
  for (int r = pbeg; r < pend; r++) {
    float v = H[(size_t)r * 128 + c];
    s += fmaxf(fmaf(v, sc, sh), 0.f);
  }
  atomicAdd(&pooled[g * 128 + c], s);
}

// ---- Head MLP ----
__global__ __launch_bounds__(256) void k_mlp(const float* __restrict__ pooled,
                                             const int* __restrict__ gstart,
                                             const float* __restrict__ W1,
                                             const float* __restrict__ b1,
                                             const float* __restrict__ W2,
                                             const float* __restrict__ b2,
                                             float* __restrict__ out) {
  __shared__ float P[64 * 128];
  __shared__ float Z[64 * 64];
  for (int i = threadIdx.x; i < 64 * 128; i += 256) {
    int g = i >> 7;
    int cnt = gstart[g + 1] - gstart[g];
    P[i] = pooled[i] / (float)(cnt > 1 ? cnt : 1);
  }
  __syncthreads();
  for (int i = threadIdx.x; i < 64 * 64; i += 256) {
    int g = i >> 6, m = i & 63;
    float acc = b1[m];
    for (int k = 0; k < 128; k++) acc += P[(g << 7) + k] * W1[k * 64 + m];
    Z[i] = fmaxf(acc, 0.f);
  }
  __syncthreads();
  if (threadIdx.x < 64) {
    int g = threadIdx.x;
    float acc = b2[0];
    for (int m = 0; m < 64; m++) acc += Z[(g << 6) + m] * W2[m];
    out[g] = 1.f / (1.f + expf(-acc));
  }
}

// ---------------------------------------------------------------------------

extern "C" void kernel_launch(void* const* d_in, const int* in_sizes, int n_in,
                              void* d_out, int out_size, void* d_ws, size_t ws_size,
                              hipStream_t stream) {
  const float* x      = (const float*)d_in[0];
  const int*   ei     = (const int*)d_in[1];
  const int*   batch  = (const int*)d_in[2];
  const float* W_enc  = (const float*)d_in[3];
  const float* b_enc  = (const float*)d_in[4];
  const float* Wc     = (const float*)d_in[5];
  const float* bc     = (const float*)d_in[6];
  const float* gamma  = (const float*)d_in[7];
  const float* beta   = (const float*)d_in[8];
  const float* W1     = (const float*)d_in[9];
  const float* b1     = (const float*)d_in[10];
  const float* W2     = (const float*)d_in[11];
  const float* b2     = (const float*)d_in[12];
  float* out = (float*)d_out;

  const int N = in_sizes[2];         // 50000
  const int E = in_sizes[1] / 2;     // 500000
  const int NL = in_sizes[6] / 128;  // 2 layers

  size_t off = 0;
  auto alloc = [&](size_t bytes) {
    void* p = (char*)d_ws + off;
    off += (bytes + 255) & ~(size_t)255;
    return p;
  };
  float* bufA   = (float*)alloc((size_t)N * 128 * 4);
  float* bufB   = (float*)alloc((size_t)N * 128 * 4);
  int*   deg    = (int*)alloc((size_t)N * 4);
  float* dinv   = (float*)alloc((size_t)N * 4);
  int*   rowptr = (int*)alloc((size_t)(N + 1) * 4);
  int*   cursor = (int*)alloc((size_t)N * 4);
  int*   colx   = (int*)alloc((size_t)(E + N) * 4);
  int*   blksum = (int*)alloc(1024 * 4);
  float* bnstat = (float*)alloc(512 * 4);   // 2 layers x (sum[128], sumsq[128])
  float* scsh   = (float*)alloc(512 * 4);   // 2 layers x (scale[128], shift[128])
  float* pooled = (float*)alloc(64 * 128 * 4);
  int*   gstart = (int*)alloc(65 * 4);

  int nbN = (N + 255) / 256;

  k_init<<<nbN, 256, 0, stream>>>(deg, pooled, bnstat, N);
  k_deg<<<(E + 255) / 256, 256, 0, stream>>>(ei, E, deg);
  k_scan_a<<<nbN, 256, 0, stream>>>(deg, N, rowptr, blksum);
  k_scan_b<<<1, 256, 0, stream>>>(blksum, nbN);
  k_scan_c<<<(N + 1 + 255) / 256, 256, 0, stream>>>(deg, N, E + N, blksum,
                                                    rowptr, cursor, dinv);
  k_fill<<<(E + N + 255) / 256, 256, 0, stream>>>(ei, E, N, cursor, colx);

  int gemmGrid = (N + 31) / 32;
  k_gemm<64><<<gemmGrid, 256, 0, stream>>>(x, W_enc, b_enc, nullptr, nullptr,
                                           bufA, N);

  for (int l = 0; l < NL; l++) {
    // layer GEMM; for l>=1 the previous layer's BN+ReLU is fused into staging
    k_gemm<128><<<gemmGrid, 256, 0, stream>>>(
        bufA, Wc + (size_t)l * 128 * 128, nullptr, dinv,
        (l > 0) ? (scsh + (l - 1) * 256) : nullptr, bufB, N);
    k_agg<<<2048, 256, 0, stream>>>(bufB, rowptr, colx, dinv, bc + l * 128,
                                    bufA, N, bnstat + l * 256);
    k_bnfinal<<<1, 128, 0, stream>>>(bnstat + l * 256, gamma + l * 128,
                                     beta + l * 128, 1.f / (float)N,
                                     scsh + l * 256);
  }

  k_gstart<<<1, 128, 0, stream>>>(batch, N, gstart);
  k_pool<<<64 * 8, 128, 0, stream>>>(bufA, scsh + (NL - 1) * 256, gstart, pooled);
  k_mlp<<<1, 256, 0, stream>>>(pooled, gstart, W1, b1, W2, b2, out);
}

// Round 3
// 437.982 us; speedup vs baseline: 1.4532x; 1.4532x over previous
//
#include <hip/hip_runtime.h>
#include <hip/hip_bf16.h>
#include <math.h>

// ---------------------------------------------------------------------------
// GCN forward on MI355X (fp32 end-to-end; no fp32 MFMA on CDNA4).
// Pipeline:
//   deg -> scan -> CSR fill (by dst, self-loops included)
//   M = W_enc @ Wc0, bfold = b_enc @ Wc0   (encoder folded into layer-0 GEMM)
//   l0: hw = (x @ M + bfold) * dinv[row]          [k_gemm<64>]
//       h  = gather-sum(hw[col]) * dinv + bc0     [k_agg, BN stats fused]
//   l1: hw = (bnrelu(h) @ Wc1) * dinv[row]        [k_gemm<128>, BN fused in]
//       h  = gather-sum(hw[col]) * dinv + bc1     [k_agg, BN stats fused]
//   pool (BN+ReLU fused) -> MLP head -> sigmoid
// GEMM k-loop: #pragma unroll 1 — round-2 lesson: full unroll spilled
// (VGPR 256, 247MB scratch writes). Body has 12 LDS reads + 64 FMA of ILP.
// ---------------------------------------------------------------------------

__global__ __launch_bounds__(256) void k_init(int* __restrict__ deg,
                                              float* __restrict__ pooled,
                                              float* __restrict__ bnstat,
                                              int N) {
  int i = blockIdx.x * 256 + threadIdx.x;
  if (i < N) deg[i] = 1;           // self-loop
  if (i < 64 * 128) pooled[i] = 0.f;
  if (i < 512) bnstat[i] = 0.f;    // sum/sumsq for both layers
}

__global__ __launch_bounds__(256) void k_deg(const int* __restrict__ ei, int E,
                                             int* __restrict__ deg) {
  int i = blockIdx.x * 256 + threadIdx.x;
  if (i < E) atomicAdd(&deg[ei[E + i]], 1);   // dst row
}

// ---- 3-kernel exclusive scan over deg[N] -> rowptr ----
__global__ __launch_bounds__(256) void k_scan_a(const int* __restrict__ deg, int N,
                                                int* __restrict__ rowptr,
                                                int* __restrict__ blksum) {
  __shared__ int s[256];
  int t = threadIdx.x;
  int i = blockIdx.x * 256 + t;
  int v = (i < N) ? deg[i] : 0;
  s[t] = v;
  __syncthreads();
  for (int off = 1; off < 256; off <<= 1) {
    int x = (t >= off) ? s[t - off] : 0;
    __syncthreads();
    s[t] += x;
    __syncthreads();
  }
  if (i < N) rowptr[i] = s[t] - v;            // exclusive (partial)
  if (t == 255) blksum[blockIdx.x] = s[255];
}

__global__ __launch_bounds__(256) void k_scan_b(int* __restrict__ blksum, int nb) {
  __shared__ int s[256];
  int t = threadIdx.x;
  int v = (t < nb) ? blksum[t] : 0;
  s[t] = v;
  __syncthreads();
  for (int off = 1; off < 256; off <<= 1) {
    int x = (t >= off) ? s[t - off] : 0;
    __syncthreads();
    s[t] += x;
    __syncthreads();
  }
  if (t < nb) blksum[t] = s[t] - v;           // exclusive
}

__global__ __launch_bounds__(256) void k_scan_c(const int* __restrict__ deg, int N,
                                                int total,
                                                const int* __restrict__ blksum,
                                                int* __restrict__ rowptr,
                                                int* __restrict__ cursor,
                                                float* __restrict__ dinv) {
  int i = blockIdx.x * 256 + threadIdx.x;
  if (i < N) {
    int rp = rowptr[i] + blksum[blockIdx.x];
    rowptr[i] = rp;
    cursor[i] = rp;
    dinv[i] = rsqrtf((float)deg[i]);
  } else if (i == N) {
    rowptr[N] = total;
  }
}

__global__ __launch_bounds__(256) void k_fill(const int* __restrict__ ei, int E, int N,
                                              int* __restrict__ cursor,
                                              int* __restrict__ colx) {
  int i = blockIdx.x * 256 + threadIdx.x;
  if (i < E) {
    int s = ei[i];
    int d = ei[E + i];
    int pos = atomicAdd(&cursor[d], 1);
    colx[pos] = s;
  } else if (i < E + N) {
    int j = i - E;
    int pos = atomicAdd(&cursor[j], 1);
    colx[pos] = j;                           // self-loop entry
  }
}

// ---- Fold encoder into layer-0 weights: M = W_enc @ Wc0, bfold = b_enc @ Wc0
__global__ __launch_bounds__(128) void k_fold(const float* __restrict__ W_enc,
                                              const float* __restrict__ b_enc,
                                              const float* __restrict__ Wc0,
                                              float* __restrict__ M,
                                              float* __restrict__ bfold) {
  int n = threadIdx.x;                 // 0..127
  int k = blockIdx.x;                  // 0..64 (64 == bias row)
  const float* arow = (k < 64) ? (W_enc + (size_t)k * 128) : b_enc;
  float acc = 0.f;
  for (int j = 0; j < 128; j++) acc = fmaf(arow[j], Wc0[(size_t)j * 128 + n], acc);
  if (k < 64) M[(size_t)k * 128 + n] = acc;
  else bfold[n] = acc;
}

// ---- GEMM: Y[N][128] = f(X)[N][K] @ W[K][128] (+bias) (*scale[row]) ----
// f = BN(scale/shift)+ReLU applied during X staging when scsh != nullptr.
// block=256 (4 waves), 32 rows/block. W and X tile both in LDS.
// Per k-group(4): 8x ds_read_b128 (X, wave-uniform broadcast -> cheap) +
// 4x ds_read_b64 (W, 2-way = free) + 64 FMA.
template <int K>
__global__ __launch_bounds__(256, 2) void k_gemm(const float* __restrict__ X,
                                                 const float* __restrict__ W,
                                                 const float* __restrict__ bias,
                                                 const float* __restrict__ scale,
                                                 const float* __restrict__ scsh,
                                                 float* __restrict__ Y, int N) {
  __shared__ float Wl[K * 128];
  __shared__ float Xl[32 * K];
  const int K4 = K / 4;

  for (int i = threadIdx.x; i < K * 32; i += 256)   // K*128/4 float4s
    ((float4*)Wl)[i] = ((const float4*)W)[i];

  int rowBlk = blockIdx.x * 32;
  for (int i = threadIdx.x; i < 32 * K4; i += 256) {
    int r = i / K4, c4 = i - r * K4;
    int row = rowBlk + r;
    if (row >= N) row = N - 1;                      // clamp (writes guarded)
    float4 v = ((const float4*)(X + (size_t)row * K))[c4];
    if (scsh) {                                     // fused BN+ReLU of prev layer
      float4 sc = ((const float4*)scsh)[c4];
      float4 sh = ((const float4*)(scsh + 128))[c4];
      v.x = fmaxf(fmaf(v.x, sc.x, sh.x), 0.f);
      v.y = fmaxf(fmaf(v.y, sc.y, sh.y), 0.f);
      v.z = fmaxf(fmaf(v.z, sc.z, sh.z), 0.f);
      v.w = fmaxf(fmaf(v.w, sc.w, sh.w), 0.f);
    }
    ((float4*)Xl)[i] = v;
  }
  __syncthreads();

  int lane = threadIdx.x & 63;
  int wv = threadIdx.x >> 6;
  int c0 = 2 * lane;
  int lr0 = wv * 8;
  int rowBase = rowBlk + lr0;

  float2 bb = make_float2(0.f, 0.f);
  if (bias) bb = *(const float2*)&bias[c0];

  float a0[8], a1[8];
#pragma unroll
  for (int r = 0; r < 8; r++) { a0[r] = bb.x; a1[r] = bb.y; }

#pragma unroll 1
  for (int k = 0; k < K; k += 4) {
    float2 w0 = *(const float2*)&Wl[(k + 0) * 128 + c0];
    float2 w1 = *(const float2*)&Wl[(k + 1) * 128 + c0];
    float2 w2 = *(const float2*)&Wl[(k + 2) * 128 + c0];
    float2 w3 = *(const float2*)&Wl[(k + 3) * 128 + c0];
    float4 xv[8];
#pragma unroll
    for (int r = 0; r < 8; r++)
      xv[r] = *(const float4*)&Xl[(lr0 + r) * K + k];
#pragma unroll
    for (int r = 0; r < 8; r++) {
      a0[r] = fmaf(xv[r].x, w0.x, a0[r]); a1[r] = fmaf(xv[r].x, w0.y, a1[r]);
      a0[r] = fmaf(xv[r].y, w1.x, a0[r]); a1[r] = fmaf(xv[r].y, w1.y, a1[r]);
      a0[r] = fmaf(xv[r].z, w2.x, a0[r]); a1[r] = fmaf(xv[r].z, w2.y, a1[r]);
      a0[r] = fmaf(xv[r].w, w3.x, a0[r]); a1[r] = fmaf(xv[r].w, w3.y, a1[r]);
    }
  }

#pragma unroll
  for (int r = 0; r < 8; r++) {
    int row = rowBase + r;
    if (row < N) {
      float s = scale ? scale[row] : 1.f;
      *(float2*)&Y[(size_t)row * 128 + c0] = make_float2(a0[r] * s, a1[r] * s);
    }
  }
}

// ---- Aggregate + fused BN stats ----
// One row per HALF-WAVE: 32 lanes x float4 = 512B per gathered row; two
// independent gather streams per wave (2x memory-level parallelism).
__global__ __launch_bounds__(256) void k_agg(const float* __restrict__ HWs,
                                             const int* __restrict__ rowptr,
                                             const int* __restrict__ colx,
                                             const float* __restrict__ dinv,
                                             const float* __restrict__ bias,
                                             float* __restrict__ Y, int N,
                                             float* __restrict__ stat) {
  int lane = threadIdx.x & 63;
  int wv = threadIdx.x >> 6;
  int half = lane >> 5;
  int l32 = lane & 31;
  int c0 = 4 * l32;
  int wid = blockIdx.x * 4 + wv;
  int nw = gridDim.x * 4;
  float4 bb = *(const float4*)&bias[c0];

  float4 sa = make_float4(0.f, 0.f, 0.f, 0.f);
  float4 qa = make_float4(0.f, 0.f, 0.f, 0.f);

  for (int base = 2 * wid; base < N; base += 2 * nw) {
    int i = base + half;
    if (i < N) {
      int beg = rowptr[i];
      int end = rowptr[i + 1];
      float4 s = make_float4(0.f, 0.f, 0.f, 0.f);
      for (int e = beg; e < end; e++) {
        int sr = colx[e];
        float4 v = *(const float4*)&HWs[(size_t)sr * 128 + c0];
        s.x += v.x; s.y += v.y; s.z += v.z; s.w += v.w;
      }
      float di = dinv[i];
      float4 o;
      o.x = fmaf(s.x, di, bb.x);
      o.y = fmaf(s.y, di, bb.y);
      o.z = fmaf(s.z, di, bb.z);
      o.w = fmaf(s.w, di, bb.w);
      *(float4*)&Y[(size_t)i * 128 + c0] = o;
      sa.x += o.x; sa.y += o.y; sa.z += o.z; sa.w += o.w;
      qa.x += o.x * o.x; qa.y += o.y * o.y; qa.z += o.z * o.z; qa.w += o.w * o.w;
    }
  }

  __shared__ float red[8][256];   // [wave*2+half][ch: 0..127 sum, 128..255 sumsq]
  int slot = wv * 2 + half;
  *(float4*)&red[slot][c0] = sa;
  *(float4*)&red[slot][128 + c0] = qa;
  __syncthreads();
  int t = threadIdx.x;
  float v = 0.f;
#pragma unroll
  for (int s8 = 0; s8 < 8; s8++) v += red[s8][t];
  atomicAdd(&stat[t], v);
}

__global__ __launch_bounds__(128) void k_bnfinal(const float* __restrict__ stat,
                                                 const float* __restrict__ gamma,
                                                 const float* __restrict__ beta,
                                                 float invN,
                                                 float* __restrict__ scsh) {
  int c = threadIdx.x;
  float mu = stat[c] * invN;
  float var = stat[128 + c] * invN - mu * mu;
  float sc = rsqrtf(var + 1e-5f) * gamma[c];
  scsh[c] = sc;
  scsh[128 + c] = beta[c] - mu * sc;
}

// ---- Pool (fused BN+ReLU of last layer) ----
__global__ __launch_bounds__(128) void k_gstart(const int* __restrict__ batch, int N,
                                                int* __restrict__ gstart) {
  int g = threadIdx.x;
  if (g <= 64) {
    int lo = 0, hi = N;
    while (lo < hi) {
      int mid = (lo + hi) >> 1;
      if (batch[mid] < g) lo = mid + 1;
      else hi = mid;
    }
    gstart[g] = lo;   // lower_bound; gstart[64] == N
  }
}

__global__ __launch_bounds__(128) void k_pool(const float* __restrict__ H,
                                              const float* __restrict__ scsh,
                                              const int* __restrict__ gstart,
                                              float* __restrict__ pooled) {
  int g = blockIdx.x >> 3;
  int part = blockIdx.x & 7;
  int c = threadIdx.x;
  float sc = scsh[c], sh = scsh[128 + c];
  int beg = gstart[g], end = gstart[g + 1];
  int len = end - beg;
  int pbeg = beg + (len * part) / 8;
  int pend = beg + (len * (part + 1)) / 8;
  float s = 0.f;
  for (int r = pbeg; r < pend; r++) {
    float v = H[(size_t)r * 128 + c];
    s += fmaxf(fmaf(v, sc, sh), 0.f);
  }
  atomicAdd(&pooled[g * 128 + c], s);
}

// ---- Head MLP ----
__global__ __launch_bounds__(256) void k_mlp(const float* __restrict__ pooled,
                                             const int* __restrict__ gstart,
                                             const float* __restrict__ W1,
                                             const float* __restrict__ b1,
                                             const float* __restrict__ W2,
                                             const float* __restrict__ b2,
                                             float* __restrict__ out) {
  __shared__ float P[64 * 128];
  __shared__ float Z[64 * 64];
  for (int i = threadIdx.x; i < 64 * 128; i += 256) {
    int g = i >> 7;
    int cnt = gstart[g + 1] - gstart[g];
    P[i] = pooled[i] / (float)(cnt > 1 ? cnt : 1);
  }
  __syncthreads();
  for (int i = threadIdx.x; i < 64 * 64; i += 256) {
    int g = i >> 6, m = i & 63;
    float acc = b1[m];
    for (int k = 0; k < 128; k++) acc += P[(g << 7) + k] * W1[k * 64 + m];
    Z[i] = fmaxf(acc, 0.f);
  }
  __syncthreads();
  if (threadIdx.x < 64) {
    int g = threadIdx.x;
    float acc = b2[0];
    for (int m = 0; m < 64; m++) acc += Z[(g << 6) + m] * W2[m];
    out[g] = 1.f / (1.f + expf(-acc));
  }
}

// ---------------------------------------------------------------------------

extern "C" void kernel_launch(void* const* d_in, const int* in_sizes, int n_in,
                              void* d_out, int out_size, void* d_ws, size_t ws_size,
                              hipStream_t stream) {
  const float* x      = (const float*)d_in[0];
  const int*   ei     = (const int*)d_in[1];
  const int*   batch  = (const int*)d_in[2];
  const float* W_enc  = (const float*)d_in[3];
  const float* b_enc  = (const float*)d_in[4];
  const float* Wc     = (const float*)d_in[5];
  const float* bc     = (const float*)d_in[6];
  const float* gamma  = (const float*)d_in[7];
  const float* beta   = (const float*)d_in[8];
  const float* W1     = (const float*)d_in[9];
  const float* b1     = (const float*)d_in[10];
  const float* W2     = (const float*)d_in[11];
  const float* b2     = (const float*)d_in[12];
  float* out = (float*)d_out;

  const int N = in_sizes[2];         // 50000
  const int E = in_sizes[1] / 2;     // 500000
  const int NL = in_sizes[6] / 128;  // 2 layers

  size_t off = 0;
  auto alloc = [&](size_t bytes) {
    void* p = (char*)d_ws + off;
    off += (bytes + 255) & ~(size_t)255;
    return p;
  };
  float* bufA   = (float*)alloc((size_t)N * 128 * 4);
  float* bufB   = (float*)alloc((size_t)N * 128 * 4);
  int*   deg    = (int*)alloc((size_t)N * 4);
  float* dinv   = (float*)alloc((size_t)N * 4);
  int*   rowptr = (int*)alloc((size_t)(N + 1) * 4);
  int*   cursor = (int*)alloc((size_t)N * 4);
  int*   colx   = (int*)alloc((size_t)(E + N) * 4);
  int*   blksum = (int*)alloc(1024 * 4);
  float* bnstat = (float*)alloc(512 * 4);   // 2 layers x (sum[128], sumsq[128])
  float* scsh   = (float*)alloc(512 * 4);   // 2 layers x (scale[128], shift[128])
  float* pooled = (float*)alloc(64 * 128 * 4);
  int*   gstart = (int*)alloc(65 * 4);
  float* Mfold  = (float*)alloc(64 * 128 * 4);
  float* bfold  = (float*)alloc(128 * 4);

  int nbN = (N + 255) / 256;

  k_init<<<nbN, 256, 0, stream>>>(deg, pooled, bnstat, N);
  k_deg<<<(E + 255) / 256, 256, 0, stream>>>(ei, E, deg);
  k_scan_a<<<nbN, 256, 0, stream>>>(deg, N, rowptr, blksum);
  k_scan_b<<<1, 256, 0, stream>>>(blksum, nbN);
  k_scan_c<<<(N + 1 + 255) / 256, 256, 0, stream>>>(deg, N, E + N, blksum,
                                                    rowptr, cursor, dinv);
  k_fill<<<(E + N + 255) / 256, 256, 0, stream>>>(ei, E, N, cursor, colx);
  k_fold<<<65, 128, 0, stream>>>(W_enc, b_enc, Wc, Mfold, bfold);

  int gemmGrid = (N + 31) / 32;

  // layer 0 (encoder folded in): hw = (x @ M + bfold) * dinv[row]
  k_gemm<64><<<gemmGrid, 256, 0, stream>>>(x, Mfold, bfold, dinv, nullptr,
                                           bufB, N);
  k_agg<<<1024, 256, 0, stream>>>(bufB, rowptr, colx, dinv, bc, bufA, N, bnstat);
  k_bnfinal<<<1, 128, 0, stream>>>(bnstat, gamma, beta, 1.f / (float)N, scsh);

  for (int l = 1; l < NL; l++) {
    k_gemm<128><<<gemmGrid, 256, 0, stream>>>(
        bufA, Wc + (size_t)l * 128 * 128, nullptr, dinv,
        scsh + (l - 1) * 256, bufB, N);
    k_agg<<<1024, 256, 0, stream>>>(bufB, rowptr, colx, dinv, bc + l * 128,
                                    bufA, N, bnstat + l * 256);
    k_bnfinal<<<1, 128, 0, stream>>>(bnstat + l * 256, gamma + l * 128,
                                     beta + l * 128, 1.f / (float)N,
                                     scsh + l * 256);
  }

  k_gstart<<<1, 128, 0, stream>>>(batch, N, gstart);
  k_pool<<<64 * 8, 128, 0, stream>>>(bufA, scsh + (NL - 1) * 256, gstart, pooled);
  k_mlp<<<1, 256, 0, stream>>>(pooled, gstart, W1, b1, W2, b2, out);
}